// Round 10
// baseline (526.550 us; speedup 1.0000x reference)
//
#include <hip/hip_runtime.h>
#include <hip/hip_bf16.h>

// ---------------------------------------------------------------------------
// LPGCNHyperConvAblation, round 10: MFMA bf16 GEMMs (16x16x32, LDS-staged
// A-tile + transposed weights), bf16 gather operands, atomic-free CSR build.
// fp32 accumulation everywhere.
// ---------------------------------------------------------------------------

typedef short bf16x8 __attribute__((ext_vector_type(8)));
typedef float f32x4v __attribute__((ext_vector_type(4)));

__device__ __forceinline__ float ldf(const void* p, int f32, long long i) {
    if (f32) return ((const float*)p)[i];
    unsigned v = ((unsigned)((const unsigned short*)p)[i]) << 16;
    return __uint_as_float(v);
}

__device__ __forceinline__ int ldi(const int* __restrict__ w, int i64, long long i, int lim) {
    int v = i64 ? w[2 * i] : w[i];
    return ((unsigned)v < (unsigned)lim) ? v : 0;
}

__device__ __forceinline__ float b2f(unsigned short u) {
    return __uint_as_float(((unsigned)u) << 16);
}
__device__ __forceinline__ unsigned short f2b(float f) {
    __hip_bfloat16 h = __float2bfloat16(f);
    return *reinterpret_cast<unsigned short*>(&h);
}
__device__ __forceinline__ float4 b2f4(ushort4 u) {
    return make_float4(b2f(u.x), b2f(u.y), b2f(u.z), b2f(u.w));
}
__device__ __forceinline__ ushort4 f2b4(float4 v) {
    ushort4 u; u.x = f2b(v.x); u.y = f2b(v.y); u.z = f2b(v.z); u.w = f2b(v.w);
    return u;
}

// --- fused dtype detection ---------------------------------------------------
struct DPtrs { const void* p[13]; int n[13]; };

__global__ void detect_k(DPtrs dp, int* __restrict__ flags) {
    int b = blockIdx.x;
    __shared__ int cnt;
    if (threadIdx.x == 0) cnt = 0;
    __syncthreads();
    int c = 0;
    if (b < 11) {
        const unsigned short* u = (const unsigned short*)dp.p[b];
        int np = dp.n[b]; if (np > 2048) np = 2048;
        for (int i = threadIdx.x; i < np; i += blockDim.x) {
            unsigned e = (u[i] >> 7) & 0xFFu;
            if (e != 0u && (e < 90u || e > 160u)) c++;
        }
        atomicAdd(&cnt, c);
        __syncthreads();
        if (threadIdx.x == 0) flags[b] = (cnt * 8 > np) ? 1 : 0;
    } else {
        const int* w = (const int*)dp.p[b];
        int np = dp.n[b]; if (np > 1024) np = 1024;
        for (int i = threadIdx.x; i < np; i += blockDim.x)
            if (w[2 * i + 1] != 0) c++;
        atomicAdd(&cnt, c);
        __syncthreads();
        if (threadIdx.x == 0) flags[b] = (cnt == 0) ? 1 : 0;
    }
}

// --- CSR build (atomic-free pipeline) ----------------------------------------
struct Item { int b1; unsigned p1; int b2; unsigned p2; };

__device__ __forceinline__ Item decode(const int* __restrict__ ew, const int* __restrict__ hw,
                                       const int* __restrict__ FL, long long i,
                                       int E, int P, int N, int HE, int shN, int shH) {
    Item it; it.b2 = -1; it.p2 = 0;
    if (i < E) {
        int g = FL[11];
        int key = ldi(ew, g, (long long)E + i, N);
        int val = ldi(ew, g, i, N);
        it.b1 = key >> shN;
        it.p1 = ((unsigned)(key & ((1 << shN) - 1)) << 20) | (unsigned)val;
    } else {
        long long j = i - E;
        int g = FL[12];
        int nd = ldi(hw, g, j, N);
        int he = ldi(hw, g, (long long)P + j, HE);
        it.b1 = 256 + (nd >> shN);
        it.p1 = ((unsigned)(nd & ((1 << shN) - 1)) << 20) | (unsigned)he;
        it.b2 = 512 + (he >> shH);
        it.p2 = ((unsigned)(he & ((1 << shH) - 1)) << 20) | (unsigned)nd;
    }
    return it;
}

__global__ void bucket_count_k(const int* __restrict__ ew, const int* __restrict__ hw,
                               const int* __restrict__ FL, int* __restrict__ gcnt,
                               int E, int P, int N, int HE, int shN, int shH) {
    __shared__ int hist[768];
    int t = threadIdx.x;
    for (int b = t; b < 768; b += 256) hist[b] = 0;
    __syncthreads();
    long long T = (long long)E + P;
    long long stride = (long long)gridDim.x * 256;
    for (long long i = (long long)blockIdx.x * 256 + t; i < T; i += stride) {
        Item it = decode(ew, hw, FL, i, E, P, N, HE, shN, shH);
        atomicAdd(&hist[it.b1], 1);
        if (it.b2 >= 0) atomicAdd(&hist[it.b2], 1);
    }
    __syncthreads();
    for (int b = t; b < 768; b += 256) {
        int h = hist[b];
        if (h) atomicAdd(&gcnt[b], h);
    }
}

__global__ void bucket_scan_k(const int* __restrict__ gcnt, int* __restrict__ bkOff,
                              int* __restrict__ gcur, int E, int P) {
    __shared__ int sh[256];
    int t = threadIdx.x;
    long long rbase[3] = {0, (long long)E, (long long)E + P};
    for (int c = 0; c < 3; c++) {
        int v = gcnt[c * 256 + t];
        sh[t] = v;
        __syncthreads();
        for (int o = 1; o < 256; o <<= 1) {
            int y = (t >= o) ? sh[t - o] : 0;
            __syncthreads();
            sh[t] += y;
            __syncthreads();
        }
        int excl = sh[t] - v;
        bkOff[c * 256 + t] = excl;
        gcur[c * 256 + t] = (int)(rbase[c] + excl);
        __syncthreads();
    }
}

#define PCHUNK 4096

__global__ void bucket_place_k(const int* __restrict__ ew, const int* __restrict__ hw,
                               const int* __restrict__ FL, int* __restrict__ gcur,
                               unsigned* __restrict__ pbuf,
                               int E, int P, int N, int HE, int shN, int shH) {
    __shared__ int hist[768];
    __shared__ int cur[768];
    long long T = (long long)E + P;
    long long start = (long long)blockIdx.x * PCHUNK;
    long long end = start + PCHUNK; if (end > T) end = T;
    int t = threadIdx.x;
    for (int b = t; b < 768; b += 256) hist[b] = 0;
    __syncthreads();
    for (long long i = start + t; i < end; i += 256) {
        Item it = decode(ew, hw, FL, i, E, P, N, HE, shN, shH);
        atomicAdd(&hist[it.b1], 1);
        if (it.b2 >= 0) atomicAdd(&hist[it.b2], 1);
    }
    __syncthreads();
    for (int b = t; b < 768; b += 256) {
        int h = hist[b];
        cur[b] = h ? atomicAdd(&gcur[b], h) : 0;
    }
    __syncthreads();
    for (long long i = start + t; i < end; i += 256) {
        Item it = decode(ew, hw, FL, i, E, P, N, HE, shN, shH);
        int s1 = atomicAdd(&cur[it.b1], 1);
        pbuf[s1] = it.p1;
        if (it.b2 >= 0) {
            int s2 = atomicAdd(&cur[it.b2], 1);
            pbuf[s2] = it.p2;
        }
    }
}

__global__ void build_k(const unsigned* __restrict__ pbuf,
                        const int* __restrict__ gcnt, const int* __restrict__ bkOff,
                        int* __restrict__ eoff, int* __restrict__ ecnt, int* __restrict__ esrc,
                        int* __restrict__ poffN, int* __restrict__ pcntN, int* __restrict__ pheL,
                        int* __restrict__ poffH, int* __restrict__ pcntH, int* __restrict__ pniL,
                        int E, int P, int N, int HE, int shN, int shH) {
    __shared__ int hist[512];
    __shared__ int offs[512];
    __shared__ int s2[256];
    int b = blockIdx.x, t = threadIdx.x;
    int csr = b >> 8, lb = b & 255;
    int sh    = (csr == 2) ? shH : shN;
    int nkeys = (csr == 2) ? HE : N;
    int span = 1 << sh;
    int keyBase = lb << sh;
    if (keyBase >= nkeys) return;
    int keyEnd = keyBase + span; if (keyEnd > nkeys) keyEnd = nkeys;
    int cnt = gcnt[b];
    long long rbase = (csr == 0) ? 0 : ((csr == 1) ? (long long)E : (long long)E + P);
    long long pstart = rbase + bkOff[b];
    int lstBase = bkOff[b];
    int* off  = (csr == 0) ? eoff : ((csr == 1) ? poffN : poffH);
    int* cntA = (csr == 0) ? ecnt : ((csr == 1) ? pcntN : pcntH);
    int* lst  = (csr == 0) ? esrc : ((csr == 1) ? pheL : pniL);

    for (int k = t; k < 512; k += 256) hist[k] = 0;
    __syncthreads();
    for (int i = t; i < cnt; i += 256)
        atomicAdd(&hist[pbuf[pstart + i] >> 20], 1);
    __syncthreads();
    int a0 = hist[2 * t], a1 = hist[2 * t + 1];
    s2[t] = a0 + a1;
    __syncthreads();
    for (int o = 1; o < 256; o <<= 1) {
        int y = (t >= o) ? s2[t - o] : 0;
        __syncthreads();
        s2[t] += y;
        __syncthreads();
    }
    int excl = s2[t] - (a0 + a1);
    offs[2 * t] = excl;
    offs[2 * t + 1] = excl + a0;
    __syncthreads();
    for (int k = keyBase + t; k < keyEnd; k += 256) {
        off[k]  = lstBase + offs[k - keyBase];
        cntA[k] = hist[k - keyBase];
    }
    __syncthreads();
    for (int i = t; i < cnt; i += 256) {
        unsigned u = pbuf[pstart + i];
        int lk = u >> 20;
        int slot = atomicAdd(&offs[lk], 1);
        lst[lstBase + slot] = (int)(u & 0xFFFFFu);
    }
}

// --- fused norm factors ------------------------------------------------------
__global__ void norms_k(const int* __restrict__ ecnt, const int* __restrict__ pcntN,
                        const int* __restrict__ pcntH, float* __restrict__ dis,
                        float* __restrict__ Dinv, float* __restrict__ Binv, int N, int HE) {
    int i = blockIdx.x * blockDim.x + threadIdx.x;
    if (i < N) dis[i] = rsqrtf((float)(ecnt[i] + 1));
    else if (i < 2 * N) { int c = pcntN[i - N]; Dinv[i - N] = c ? (1.f / (float)c) : 0.f; }
    else if (i < 2 * N + HE) { int c = pcntH[i - 2 * N]; Binv[i - 2 * N] = c ? (1.f / (float)c) : 0.f; }
}

// --- Wlp2 = W_c2 @ W_lp, bias2 = b_c2 @ W_lp + b_lp  (LDS-staged) ------------
__global__ void wlp2_k(const void* Wc2, const int* fWc2, const void* Wlp, const int* fWlp,
                       const void* bc2, const int* fbc2, const void* blp, const int* fblp,
                       float* __restrict__ Wlp2, float* __restrict__ bias2, int NC) {
    extern __shared__ float sm[];
    float* sW2 = sm;
    float* sLP = sm + 64 * NC;
    int t = threadIdx.x;
    int fw2 = fWc2[0], flp = fWlp[0];
    for (int e = t; e < 64 * NC; e += blockDim.x) sW2[e] = ldf(Wc2, fw2, e);
    for (int e = t; e < NC * NC; e += blockDim.x) sLP[e] = ldf(Wlp, flp, e);
    __syncthreads();
    for (int e = t; e < 64 * NC; e += blockDim.x) {
        int r = e / NC, c = e % NC;
        float s = 0.f;
        for (int k = 0; k < NC; k++) s = fmaf(sW2[r * NC + k], sLP[k * NC + c], s);
        Wlp2[e] = s;
    }
    if (t < NC) {
        float s = ldf(blp, fblp[0], t);
        int fb2 = fbc2[0];
        for (int k = 0; k < NC; k++) s = fmaf(ldf(bc2, fb2, k), sLP[k * NC + t], s);
        bias2[t] = s;
    }
}

// --- bf16 gathers (unchanged from round 9) -----------------------------------
__global__ void gat_n2e_k(const ushort4* __restrict__ xw, const int* __restrict__ off,
                          const int* __restrict__ cnt, const int* __restrict__ lst,
                          const float* __restrict__ Binv, ushort4* __restrict__ ef, int HE) {
    int idx = blockIdx.x * blockDim.x + threadIdx.x;
    int e = idx >> 4, l = idx & 15;
    if (e >= HE) return;
    int o = off[e], c = cnt[e];
    float4 a = make_float4(0.f, 0.f, 0.f, 0.f);
    int j = 0;
    for (; j + 4 <= c; j += 4) {
        int s0 = lst[o + j], s1 = lst[o + j + 1], s2 = lst[o + j + 2], s3 = lst[o + j + 3];
        float4 v0 = b2f4(xw[((long long)s0 << 4) + l]);
        float4 v1 = b2f4(xw[((long long)s1 << 4) + l]);
        float4 v2 = b2f4(xw[((long long)s2 << 4) + l]);
        float4 v3 = b2f4(xw[((long long)s3 << 4) + l]);
        a.x += (v0.x + v1.x) + (v2.x + v3.x);
        a.y += (v0.y + v1.y) + (v2.y + v3.y);
        a.z += (v0.z + v1.z) + (v2.z + v3.z);
        a.w += (v0.w + v1.w) + (v2.w + v3.w);
    }
    for (; j < c; j++) {
        float4 v = b2f4(xw[((long long)lst[o + j] << 4) + l]);
        a.x += v.x; a.y += v.y; a.z += v.z; a.w += v.w;
    }
    float bi = Binv[e];
    a.x *= bi; a.y *= bi; a.z *= bi; a.w *= bi;
    ef[((long long)e << 4) + l] = f2b4(a);
}

template <bool RELU>
__global__ void gat_e2n_k(const ushort4* __restrict__ ef, const int* __restrict__ off,
                          const int* __restrict__ cnt, const int* __restrict__ lst,
                          const float* __restrict__ Dinv, const void* __restrict__ bias,
                          const int* __restrict__ fb, ushort4* __restrict__ out, int N) {
    int idx = blockIdx.x * blockDim.x + threadIdx.x;
    int w = idx >> 4, l = idx & 15;
    if (w >= N) return;
    int o = off[w], c = cnt[w];
    float4 a = make_float4(0.f, 0.f, 0.f, 0.f);
    int j = 0;
    for (; j + 4 <= c; j += 4) {
        int s0 = lst[o + j], s1 = lst[o + j + 1], s2 = lst[o + j + 2], s3 = lst[o + j + 3];
        float4 v0 = b2f4(ef[((long long)s0 << 4) + l]);
        float4 v1 = b2f4(ef[((long long)s1 << 4) + l]);
        float4 v2 = b2f4(ef[((long long)s2 << 4) + l]);
        float4 v3 = b2f4(ef[((long long)s3 << 4) + l]);
        a.x += (v0.x + v1.x) + (v2.x + v3.x);
        a.y += (v0.y + v1.y) + (v2.y + v3.y);
        a.z += (v0.z + v1.z) + (v2.z + v3.z);
        a.w += (v0.w + v1.w) + (v2.w + v3.w);
    }
    for (; j < c; j++) {
        float4 v = b2f4(ef[((long long)lst[o + j] << 4) + l]);
        a.x += v.x; a.y += v.y; a.z += v.z; a.w += v.w;
    }
    float di = Dinv[w];
    int fbv = fb[0];
    float4 b = make_float4(ldf(bias, fbv, 4 * l), ldf(bias, fbv, 4 * l + 1),
                           ldf(bias, fbv, 4 * l + 2), ldf(bias, fbv, 4 * l + 3));
    a.x = a.x * di + b.x; a.y = a.y * di + b.y;
    a.z = a.z * di + b.z; a.w = a.w * di + b.w;
    if (RELU) {
        a.x = fmaxf(a.x, 0.f); a.y = fmaxf(a.y, 0.f);
        a.z = fmaxf(a.z, 0.f); a.w = fmaxf(a.w, 0.f);
    }
    out[((long long)w << 4) + l] = f2b4(a);
}

template <bool RELU>
__global__ void gcn_gat_k(const ushort4* __restrict__ y, const int* __restrict__ off,
                          const int* __restrict__ cnt, const int* __restrict__ lst,
                          const float* __restrict__ dis, const void* __restrict__ bias,
                          const int* __restrict__ fb, ushort4* __restrict__ out, int N) {
    int idx = blockIdx.x * blockDim.x + threadIdx.x;
    int w = idx >> 4, l = idx & 15;
    if (w >= N) return;
    int o = off[w], c = cnt[w];
    float4 a = b2f4(y[((long long)w << 4) + l]);
    int j = 0;
    for (; j + 4 <= c; j += 4) {
        int s0 = lst[o + j], s1 = lst[o + j + 1], s2 = lst[o + j + 2], s3 = lst[o + j + 3];
        float4 v0 = b2f4(y[((long long)s0 << 4) + l]);
        float4 v1 = b2f4(y[((long long)s1 << 4) + l]);
        float4 v2 = b2f4(y[((long long)s2 << 4) + l]);
        float4 v3 = b2f4(y[((long long)s3 << 4) + l]);
        a.x += (v0.x + v1.x) + (v2.x + v3.x);
        a.y += (v0.y + v1.y) + (v2.y + v3.y);
        a.z += (v0.z + v1.z) + (v2.z + v3.z);
        a.w += (v0.w + v1.w) + (v2.w + v3.w);
    }
    for (; j < c; j++) {
        float4 v = b2f4(y[((long long)lst[o + j] << 4) + l]);
        a.x += v.x; a.y += v.y; a.z += v.z; a.w += v.w;
    }
    float dd = dis[w];
    int fbv = fb[0];
    float4 b = make_float4(ldf(bias, fbv, 4 * l), ldf(bias, fbv, 4 * l + 1),
                           ldf(bias, fbv, 4 * l + 2), ldf(bias, fbv, 4 * l + 3));
    a.x = a.x * dd + b.x; a.y = a.y * dd + b.y;
    a.z = a.z * dd + b.z; a.w = a.w * dd + b.w;
    if (RELU) {
        a.x = fmaxf(a.x, 0.f); a.y = fmaxf(a.y, 0.f);
        a.z = fmaxf(a.z, 0.f); a.w = fmaxf(a.w, 0.f);
    }
    out[((long long)w << 4) + l] = f2b4(a);
}

__global__ void gcn_gatM_k(const ushort4* __restrict__ y2, const int* __restrict__ off,
                           const int* __restrict__ cnt, const int* __restrict__ lst,
                           const float* __restrict__ dis, const float* __restrict__ bias2,
                           float4* __restrict__ out4, int N, int nc4, int npw) {
    int idx = blockIdx.x * blockDim.x + threadIdx.x;
    int wave = idx >> 6, l64 = idx & 63;
    int grp = l64 / 10, li = l64 - grp * 10;
    if (nc4 != 10) { grp = l64 / nc4; li = l64 - grp * nc4; }
    int w = wave * npw + grp;
    if (grp >= npw || w >= N) return;
    int o = off[w], c = cnt[w];
    float4 a = b2f4(y2[(long long)w * nc4 + li]);
    int j = 0;
    for (; j + 4 <= c; j += 4) {
        int s0 = lst[o + j], s1 = lst[o + j + 1], s2 = lst[o + j + 2], s3 = lst[o + j + 3];
        float4 v0 = b2f4(y2[(long long)s0 * nc4 + li]);
        float4 v1 = b2f4(y2[(long long)s1 * nc4 + li]);
        float4 v2 = b2f4(y2[(long long)s2 * nc4 + li]);
        float4 v3 = b2f4(y2[(long long)s3 * nc4 + li]);
        a.x += (v0.x + v1.x) + (v2.x + v3.x);
        a.y += (v0.y + v1.y) + (v2.y + v3.y);
        a.z += (v0.z + v1.z) + (v2.z + v3.z);
        a.w += (v0.w + v1.w) + (v2.w + v3.w);
    }
    for (; j < c; j++) {
        float4 v = b2f4(y2[(long long)lst[o + j] * nc4 + li]);
        a.x += v.x; a.y += v.y; a.z += v.z; a.w += v.w;
    }
    float dd = dis[w];
    float4 b = *(const float4*)&bias2[4 * li];
    a.x = a.x * dd + b.x; a.y = a.y * dd + b.y;
    a.z = a.z * dd + b.z; a.w = a.w * dd + b.w;
    out4[(long long)w * nc4 + li] = a;
}

// --- MFMA bf16 GEMM: 64-row tile, NF*16 cols, 4 waves x (16 rows) ------------
// C[r][c] = sum_k A[r][k] * W[k][c]; A fp32/flag or bf16 workspace; bf16 out.
// LDS: As[64][K+8] bf16, Wt[NF*16][K+8] bf16 (weights transposed). K%32==0.
template <int NF, bool ABF16, bool SCALE>
__global__ __launch_bounds__(256)
void mfma_gemm_k(const void* __restrict__ A, const int* __restrict__ fA,
                 const void* __restrict__ B, const int* __restrict__ fB,
                 const float* __restrict__ dscale,
                 unsigned short* __restrict__ C, int NR, int K, int M) {
    extern __shared__ unsigned short sm16[];
    const int KP = K + 8;
    unsigned short* As = sm16;             // 64 * KP
    unsigned short* Wt = sm16 + 64 * KP;   // NF*16 * KP
    const int t = threadIdx.x;
    const int af = fA ? fA[0] : 1;
    const int bf = fB ? fB[0] : 1;
    const long long m0 = (long long)blockIdx.x * 64;

    // stage A tile (bf16)
    for (int idx = t * 4; idx < 64 * K; idx += 1024) {
        int row = idx / K, col = idx - row * K;
        long long r = m0 + row;
        ushort4 o = make_ushort4(0, 0, 0, 0);
        if (r < NR) {
            long long base = r * (long long)K + col;
            if (ABF16 || !af) o = *(const ushort4*)((const unsigned short*)A + base);
            else o = f2b4(*(const float4*)((const float*)A + base));
        }
        *(ushort4*)&As[row * KP + col] = o;
    }
    // stage W transposed (bf16)
    for (int e = t; e < NF * 16 * K; e += 256) {
        int n = e / K, k = e - n * K;
        float v = (n < M) ? ldf(B, bf, (long long)k * M + n) : 0.f;
        Wt[n * KP + k] = f2b(v);
    }
    __syncthreads();

    const int w = t >> 6, l = t & 63;
    const int m = l & 15, q = l >> 4;
    f32x4v acc[NF];
#pragma unroll
    for (int f = 0; f < NF; f++) acc[f] = (f32x4v){0.f, 0.f, 0.f, 0.f};

    const int aBase = (w * 16 + m) * KP + q * 8;
    for (int k0 = 0; k0 < K; k0 += 32) {
        bf16x8 afr = *(const bf16x8*)&As[aBase + k0];
#pragma unroll
        for (int f = 0; f < NF; f++) {
            bf16x8 bfr = *(const bf16x8*)&Wt[(f * 16 + m) * KP + q * 8 + k0];
            acc[f] = __builtin_amdgcn_mfma_f32_16x16x32_bf16(afr, bfr, acc[f], 0, 0, 0);
        }
    }

    // epilogue: C/D layout col=lane&15, row=quad*4+reg
#pragma unroll
    for (int reg = 0; reg < 4; reg++) {
        long long r = m0 + w * 16 + q * 4 + reg;
        if (r < NR) {
            float s = SCALE ? dscale[r] : 1.f;
#pragma unroll
            for (int f = 0; f < NF; f++) {
                int col = f * 16 + m;
                if (col < M) C[r * (long long)M + col] = f2b(acc[f][reg] * s);
            }
        }
    }
}

// concat variant: A = [x (128, fp32/flag) | A2 (64, bf16)], K=192, M=64, scaled
__global__ __launch_bounds__(256)
void mfma_gemmcat_k(const void* __restrict__ A, const int* __restrict__ fA,
                    const unsigned short* __restrict__ A2,
                    const void* __restrict__ B, const int* __restrict__ fB,
                    const float* __restrict__ dscale,
                    unsigned short* __restrict__ C, int NR, int M) {
    extern __shared__ unsigned short sm16[];
    const int K = 192, KP = 200;
    unsigned short* As = sm16;
    unsigned short* Wt = sm16 + 64 * KP;
    const int t = threadIdx.x;
    const int af = fA ? fA[0] : 1;
    const int bf = fB ? fB[0] : 1;
    const long long m0 = (long long)blockIdx.x * 64;

    for (int idx = t * 4; idx < 64 * K; idx += 1024) {
        int row = idx / K, col = idx - row * K;
        long long r = m0 + row;
        ushort4 o = make_ushort4(0, 0, 0, 0);
        if (r < NR) {
            if (col < 128) {
                long long base = r * 128 + col;
                if (!af) o = *(const ushort4*)((const unsigned short*)A + base);
                else o = f2b4(*(const float4*)((const float*)A + base));
            } else {
                o = *(const ushort4*)&A2[r * 64 + (col - 128)];
            }
        }
        *(ushort4*)&As[row * KP + col] = o;
    }
    for (int e = t; e < 64 * K; e += 256) {
        int n = e / K, k = e - n * K;
        Wt[n * KP + k] = f2b(ldf(B, bf, (long long)k * M + n));
    }
    __syncthreads();

    const int w = t >> 6, l = t & 63;
    const int m = l & 15, q = l >> 4;
    f32x4v acc[4];
#pragma unroll
    for (int f = 0; f < 4; f++) acc[f] = (f32x4v){0.f, 0.f, 0.f, 0.f};

    const int aBase = (w * 16 + m) * KP + q * 8;
#pragma unroll
    for (int k0 = 0; k0 < K; k0 += 32) {
        bf16x8 afr = *(const bf16x8*)&As[aBase + k0];
#pragma unroll
        for (int f = 0; f < 4; f++) {
            bf16x8 bfr = *(const bf16x8*)&Wt[(f * 16 + m) * KP + q * 8 + k0];
            acc[f] = __builtin_amdgcn_mfma_f32_16x16x32_bf16(afr, bfr, acc[f], 0, 0, 0);
        }
    }
#pragma unroll
    for (int reg = 0; reg < 4; reg++) {
        long long r = m0 + w * 16 + q * 4 + reg;
        if (r < NR) {
            float s = dscale[r];
#pragma unroll
            for (int f = 0; f < 4; f++)
                C[r * (long long)M + f * 16 + m] = f2b(acc[f][reg] * s);
        }
    }
}

static inline dim3 g1d(long long n, int b) { return dim3((unsigned)((n + b - 1) / b)); }
static inline int imin(int a, int b) { return a < b ? a : b; }

extern "C" void kernel_launch(void* const* d_in, const int* in_sizes, int n_in,
                              void* d_out, int out_size, void* d_ws, size_t ws_size,
                              hipStream_t stream) {
    const int N  = in_sizes[0] / 128;   // 100000
    const int E  = in_sizes[1] / 2;     // 1600000
    const int P  = in_sizes[2] / 2;     // 800000
    const int HE = 20000;
    const int NC = in_sizes[9] / 64;    // 40
    const int nc4 = NC / 4;             // 10
    const int npw = 64 / nc4;           // 6

    const void* x    = d_in[0];
    const int*  ew   = (const int*)d_in[1];
    const int*  hw   = (const int*)d_in[2];
    const void* W_h1 = d_in[3];
    const void* b_h1 = d_in[4];
    const void* W_h2 = d_in[5];
    const void* b_h2 = d_in[6];
    const void* W_c1 = d_in[7];
    const void* b_c1 = d_in[8];
    const void* W_c2 = d_in[9];
    const void* b_c2 = d_in[10];
    const void* W_lp = d_in[11];
    const void* b_lp = d_in[12];

    int shN = 0; while (((N - 1) >> shN) >= 256) shN++;   // 9
    int shH = 0; while (((HE - 1) >> shH) >= 256) shH++;  // 7

    // ---- workspace ----
    char* wp = (char*)d_ws;
    auto allocF = [&](size_t n) { float* p = (float*)wp; wp += n * 4; return p; };
    auto allocI = [&](size_t n) { int* p = (int*)wp; wp += n * 4; return p; };
    unsigned short* ub  = (unsigned short*)allocF((size_t)N * 32);   // bf16 N*64
    unsigned short* hb  = (unsigned short*)allocF((size_t)N * 32);   // bf16 N*64
    unsigned short* efb = (unsigned short*)allocF((size_t)HE * 32);  // bf16 HE*64
    float* dis   = allocF(N);
    float* Dinv  = allocF(N);
    float* Binv  = allocF(HE);
    float* Wlp2  = allocF((size_t)64 * NC);
    float* bias2 = allocF(NC);
    int* ecnt  = allocI(N);
    int* pcntN = allocI(N);
    int* pcntH = allocI(HE);
    int* eoff  = allocI(N);
    int* poffN = allocI(N);
    int* poffH = allocI(HE);
    int* esrc  = allocI(E);
    int* pheL  = allocI(P);
    int* pniL  = allocI(P);
    int* gBkt  = allocI(768);
    int* bkOff = allocI(768);
    int* gcur  = allocI(768);
    int* FL    = allocI(16);
    unsigned* pbuf = (unsigned*)allocI((size_t)E + 2 * (size_t)P);

    dim3 b256(256), d1(1);

    // ---- dtype detection ----
    DPtrs dp;
    const void* farr[11] = {x, W_h1, b_h1, W_h2, b_h2, W_c1, b_c1, W_c2, b_c2, W_lp, b_lp};
    const int   fsz[11]  = {in_sizes[0], in_sizes[3], in_sizes[4], in_sizes[5], in_sizes[6],
                            in_sizes[7], in_sizes[8], in_sizes[9], in_sizes[10], in_sizes[11],
                            in_sizes[12]};
    for (int i = 0; i < 11; ++i) { dp.p[i] = farr[i]; dp.n[i] = fsz[i]; }
    dp.p[11] = ew; dp.n[11] = imin(E, 1024);
    dp.p[12] = hw; dp.n[12] = imin(P, 1024);
    detect_k<<<dim3(13), b256, 0, stream>>>(dp, FL);
    const int* fX   = FL + 0;
    const int* fWh1 = FL + 1,  *fbh1 = FL + 2;
    const int* fWh2 = FL + 3,  *fbh2 = FL + 4;
    const int* fWc1 = FL + 5,  *fbc1 = FL + 6;
    const int* fWc2 = FL + 7,  *fbc2 = FL + 8;
    const int* fWlp = FL + 9,  *fblp = FL + 10;

    // ---- CSR build ----
    hipMemsetAsync(gBkt, 0, 768 * 4, stream);
    bucket_count_k<<<dim3(512), b256, 0, stream>>>(ew, hw, FL, gBkt, E, P, N, HE, shN, shH);
    bucket_scan_k<<<d1, b256, 0, stream>>>(gBkt, bkOff, gcur, E, P);
    {
        long long T = (long long)E + P;
        int nChunks = (int)((T + PCHUNK - 1) / PCHUNK);
        bucket_place_k<<<dim3(nChunks), b256, 0, stream>>>(ew, hw, FL, gcur, pbuf,
                                                           E, P, N, HE, shN, shH);
    }
    build_k<<<dim3(768), b256, 0, stream>>>(pbuf, gBkt, bkOff,
                                            eoff, ecnt, esrc,
                                            poffN, pcntN, pheL,
                                            poffH, pcntH, pniL,
                                            E, P, N, HE, shN, shH);

    // ---- norms + fused tail weights ----
    norms_k<<<g1d(2 * N + HE, 256), b256, 0, stream>>>(ecnt, pcntN, pcntH, dis, Dinv, Binv, N, HE);
    wlp2_k<<<d1, b256, (64 * NC + NC * NC) * 4, stream>>>(
        W_c2, fWc2, W_lp, fWlp, b_c2, fbc2, b_lp, fblp, Wlp2, bias2, NC);

    const dim3 gemmGrid((N + 63) / 64);
    const dim3 gatN16(g1d((long long)N * 16, 256));
    const dim3 gatH16(g1d((long long)HE * 16, 256));
    const dim3 gatNC(g1d((long long)((N + npw - 1) / npw) * 64, 256));

    const int lds128 = (64 + 64) * 136 * 2;   // K=128
    const int lds64a = (64 + 64) * 72 * 2;    // K=64, NF=4
    const int lds64b = (64 + 48) * 72 * 2;    // K=64, NF=3
    const int lds192 = (64 + 64) * 200 * 2;   // K=192

    // ---- hyperconv 1: ub = bf16(x @ W_h1) ----
    mfma_gemm_k<4, false, false><<<gemmGrid, b256, lds128, stream>>>(
        x, fX, W_h1, fWh1, nullptr, ub, N, 128, 64);
    gat_n2e_k<<<gatH16, b256, 0, stream>>>((const ushort4*)ub, poffH, pcntH, pniL, Binv, (ushort4*)efb, HE);
    gat_e2n_k<true><<<gatN16, b256, 0, stream>>>((const ushort4*)efb, poffN, pcntN, pheL, Dinv, b_h1, fbh1, (ushort4*)hb, N);

    // ---- hyperconv 2: ub = bf16(hb @ W_h2) ----
    mfma_gemm_k<4, true, false><<<gemmGrid, b256, lds64a, stream>>>(
        hb, nullptr, W_h2, fWh2, nullptr, ub, N, 64, 64);
    gat_n2e_k<<<gatH16, b256, 0, stream>>>((const ushort4*)ub, poffH, pcntH, pniL, Binv, (ushort4*)efb, HE);
    gat_e2n_k<false><<<gatN16, b256, 0, stream>>>((const ushort4*)efb, poffN, pcntN, pheL, Dinv, b_h2, fbh2, (ushort4*)hb, N);
    // hb = x_hyper (bf16)

    // ---- gcn 1: ub = bf16(([x|hb] @ W_c1) * dis), gather -> hb ----
    mfma_gemmcat_k<<<gemmGrid, b256, lds192, stream>>>(x, fX, hb, W_c1, fWc1, dis, ub, N, 64);
    gcn_gat_k<true><<<gatN16, b256, 0, stream>>>((const ushort4*)ub, eoff, ecnt, esrc, dis, b_c1, fbc1, (ushort4*)hb, N);

    // ---- gcn 2 + final linear fused: ub = bf16((hb @ Wlp2) * dis), gather ----
    mfma_gemm_k<3, true, true><<<gemmGrid, b256, lds64b, stream>>>(
        hb, nullptr, Wlp2, nullptr, dis, ub, N, 64, NC);
    gcn_gatM_k<<<gatNC, b256, 0, stream>>>((const ushort4*)ub, eoff, ecnt, esrc, dis, bias2, (float4*)d_out, N, nc4, npw);
}